// Round 2
// baseline (219.006 us; speedup 1.0000x reference)
//
#include <hip/hip_runtime.h>
#include <hip/hip_bf16.h>

typedef __attribute__((ext_vector_type(8))) short short8;   // 8 x bf16 (4 VGPRs)
typedef __attribute__((ext_vector_type(4))) float floatx4;  // MFMA acc

#define XS_STRIDE 72    // ushorts; xs[204][72] = 29376 B at smem+0, DEAD after A2a frag preload
#define QOFF 26112      // byte offset of Q region (26112 = 204*128, 0 mod 128B -> same bank phase)
// ys split layout (fixes plo/phi half-bank reads):
//   P region [204][128B] at smem+0      : chunk g (16B) = channels g*16 .. g*16+7 (bf16)
//   Q region [204][128B] at smem+26112  : chunk g (16B) = channels g*16+8 .. g*16+15
//   per-row XOR swizzle: physical chunk = logical chunk ^ ((px>>2)&3)  (byte ^= ((px>>2)&3)<<4)
//   -> phase-B reads are base+lane*16 contiguous (0-conflict); A2b writes spread kq groups (2-way).
// ostage (deferred): after pass oy, pixel-row band oy of P and Q is dead (34*128 = 4352 B each).
//   After pass1: P rows 0..67 (8704 B) + Q rows 0..67 (8704 B) dead ->
//   chunk A (ox 0..15) at smem+0, chunk B (ox 16..31) at smem+QOFF, each [16][132] f32 = 8448 B.
// LDS total 52224 B -> 3 blocks/CU.

__device__ __forceinline__ ushort f2bf(float f) {
    union { __hip_bfloat16 h; ushort u; } cv;
    cv.h = __float2bfloat16(f);
    return cv.u;
}
__device__ __forceinline__ float bflo(unsigned int u) { return __uint_as_float(u << 16); }
__device__ __forceinline__ float bfhi(unsigned int u) { return __uint_as_float(u & 0xffff0000u); }

__device__ __forceinline__ float dot8(uint4 p, const float* cf) {
    return bflo(p.x)*cf[0] + bfhi(p.x)*cf[1] + bflo(p.y)*cf[2] + bfhi(p.y)*cf[3]
         + bflo(p.z)*cf[4] + bfhi(p.z)*cf[5] + bflo(p.w)*cf[6] + bfhi(p.w)*cf[7];
}
__device__ __forceinline__ void fma8(uint4 p, float a, float* o) {
    o[0] += a*bflo(p.x); o[1] += a*bfhi(p.x); o[2] += a*bflo(p.y); o[3] += a*bfhi(p.y);
    o[4] += a*bflo(p.z); o[5] += a*bfhi(p.z); o[6] += a*bflo(p.w); o[7] += a*bfhi(p.w);
}

// 8-lane (same-pixel) reduce: xor1/xor2 on VALU via DPP quad_perm, xor4 via shfl.
__device__ __forceinline__ float gsum8(float v) {
    v += __int_as_float(__builtin_amdgcn_update_dpp(0, __float_as_int(v), 0xB1, 0xF, 0xF, false)); // xor1
    v += __int_as_float(__builtin_amdgcn_update_dpp(0, __float_as_int(v), 0x4E, 0xF, 0xF, false)); // xor2
    v += __shfl_xor(v, 4);                                                                          // xor4
    return v;
}

// ---- phase-B macros (macros, not lambdas: guarantee full inline + static o[] indexing) ----
#define COMPUTE_PASS(OY, OVEC)                                                          \
    {                                                                                   \
        const int pc = ((OY) + 1) * 34 + (ox + 1);                                      \
        uint4 plo[9], phi[9];                                                           \
        _Pragma("unroll")                                                               \
        for (int n = 0; n < 9; ++n) {                                                   \
            int pi = pc + (n / 3 - 1) * 34 + (n % 3 - 1);                               \
            const char* pp = smc + pi * 128 + ((g * 16) ^ (((pi >> 2) & 3) << 4));      \
            plo[n] = *(const uint4*)pp;                                                 \
            phi[n] = *(const uint4*)(pp + QOFF);                                        \
        }                                                                               \
        float cf[16];                                                                   \
        {                                                                               \
            uint4 c0 = plo[4], c1 = phi[4];                                             \
            cf[0]=bflo(c0.x); cf[1]=bfhi(c0.x); cf[2]=bflo(c0.y); cf[3]=bfhi(c0.y);     \
            cf[4]=bflo(c0.z); cf[5]=bfhi(c0.z); cf[6]=bflo(c0.w); cf[7]=bfhi(c0.w);     \
            cf[8]=bflo(c1.x); cf[9]=bfhi(c1.x); cf[10]=bflo(c1.y); cf[11]=bfhi(c1.y);   \
            cf[12]=bflo(c1.z); cf[13]=bfhi(c1.z); cf[14]=bflo(c1.w); cf[15]=bfhi(c1.w); \
        }                                                                               \
        float s[9];                                                                     \
        _Pragma("unroll")                                                               \
        for (int n = 0; n < 9; ++n)                                                     \
            s[n] = dot8(plo[n], cf) + dot8(phi[n], cf + 8);                             \
        _Pragma("unroll")                                                               \
        for (int n = 0; n < 9; ++n)                                                     \
            s[n] = gsum8(s[n]) * 0.08838834764831845f;  /* 1/sqrt(128) */               \
        float m = s[0];                                                                 \
        _Pragma("unroll")                                                               \
        for (int n = 1; n < 9; ++n) m = fmaxf(m, s[n]);                                 \
        float e[9], sum = 0.f;                                                          \
        _Pragma("unroll")                                                               \
        for (int n = 0; n < 9; ++n) { e[n] = __expf(s[n] - m); sum += e[n]; }           \
        float inv = 1.f / sum;                                                          \
        _Pragma("unroll")                                                               \
        for (int j = 0; j < 16; ++j) OVEC[j] = 0.f;                                     \
        _Pragma("unroll")                                                               \
        for (int n = 0; n < 9; ++n) {                                                   \
            float a = e[n] * inv;                                                       \
            fma8(plo[n], a, OVEC);                                                      \
            fma8(phi[n], a, OVEC + 8);                                                  \
        }                                                                               \
    }

#define STAGE_PASS(OVEC)                                                                \
    {                                                                                   \
        float* op = (float*)(smc + (ox < 16 ? 0 : QOFF)) + (ox & 15) * 132 + g * 16;    \
        _Pragma("unroll")                                                               \
        for (int k = 0; k < 4; ++k)                                                     \
            *(float4*)(op + 4 * k) =                                                    \
                make_float4(OVEC[4*k], OVEC[4*k+1], OVEC[4*k+2], OVEC[4*k+3]);          \
    }

#define COOP_STORE(OY)                                                                  \
    {                                                                                   \
        int c = tid >> 1, half = tid & 1;                                               \
        const float* ost = (const float*)(smc + (half ? QOFF : 0));                     \
        float tmp[16];                                                                  \
        _Pragma("unroll")                                                               \
        for (int j = 0; j < 16; ++j) tmp[j] = ost[j * 132 + c];                         \
        float* og = out + ((size_t)((b * 128 + c) * 128 + (h0 + (OY)))) * 128           \
                    + w0 + half * 16;                                                   \
        _Pragma("unroll")                                                               \
        for (int k = 0; k < 4; ++k)                                                     \
            *(float4*)(og + 4 * k) = make_float4(tmp[4*k], tmp[4*k+1], tmp[4*k+2], tmp[4*k+3]); \
    }

__global__ __launch_bounds__(256, 3)
void attn_conv_fused(const float* __restrict__ x, const float* __restrict__ Wc,
                     const float* __restrict__ bc, float* __restrict__ out) {
    __shared__ __align__(16) unsigned char smem[52224];
    ushort* xs = (ushort*)smem;
    char* smc = (char*)smem;

    const int tid = threadIdx.x;
    // XCD-chunked swizzle (bijective, 1024 = 8*128): XCD k owns batch k entirely;
    // within an XCD, w-tiles fastest then h-bands -> halo rows stay L2-resident.
    const int rid = ((blockIdx.x & 7) << 7) | (blockIdx.x >> 3);
    const int b   = rid >> 7;
    const int h0  = ((rid >> 2) & 31) * 4;
    const int w0  = (rid & 3) * 32;
    const int lane = tid & 63;
    const int wv   = tid >> 6;

    // ---------------- Phase A0: stage x tile transposed -> xs[px][ci] bf16 ----
    if (tid < 204) {
        int py  = (tid * 965) >> 15;          // tid / 34 (exact for tid<208)
        int pxx = tid - py * 34;
        int gh = h0 + py - 1, gw = w0 + pxx - 1;
        bool inb = (gh >= 0 && gh < 128 && gw >= 0 && gw < 128);
        ushort* dst = xs + tid * XS_STRIDE;
        if (inb) {
            const float* xp = x + (b * 64) * 16384 + gh * 128 + gw;
            #pragma unroll
            for (int c0 = 0; c0 < 64; c0 += 4) {
                float v0 = xp[(c0 + 0) << 14];
                float v1 = xp[(c0 + 1) << 14];
                float v2 = xp[(c0 + 2) << 14];
                float v3 = xp[(c0 + 3) << 14];
                unsigned int u01 = (unsigned int)f2bf(v0) | ((unsigned int)f2bf(v1) << 16);
                unsigned int u23 = (unsigned int)f2bf(v2) | ((unsigned int)f2bf(v3) << 16);
                *(uint2*)(dst + c0) = make_uint2(u01, u23);
            }
        } else {
            #pragma unroll
            for (int c0 = 0; c0 < 64; c0 += 4)
                *(uint2*)(dst + c0) = make_uint2(0u, 0u);
        }
    }

    // ---------------- Phase A1: W fragments (B-operand) from global ----------
    const int col = lane & 15;
    const int kq  = lane >> 4;
    short8 bw[8][2];
    float  bias[8];
    #pragma unroll
    for (int t = 0; t < 8; ++t) {
        int c = t * 16 + col;
        bias[t] = bc[c];
        #pragma unroll
        for (int half = 0; half < 2; ++half) {
            const float* wp = Wc + c * 64 + half * 32 + kq * 8;
            float4 wa = *(const float4*)wp;
            float4 wb = *(const float4*)(wp + 4);
            short8 f;
            f[0] = (short)f2bf(wa.x); f[1] = (short)f2bf(wa.y);
            f[2] = (short)f2bf(wa.z); f[3] = (short)f2bf(wa.w);
            f[4] = (short)f2bf(wb.x); f[5] = (short)f2bf(wb.y);
            f[6] = (short)f2bf(wb.z); f[7] = (short)f2bf(wb.w);
            bw[t][half] = f;
        }
    }
    __syncthreads();

    // ---------------- Phase A2a: preload this wave's A-fragments (xs dies) ----
    short8 af0[4], af1[4];
    #pragma unroll
    for (int i = 0; i < 4; ++i) {
        int mt = wv + i * 4;
        if (mt < 13) {
            const ushort* ap = xs + (mt * 16 + col) * XS_STRIDE + kq * 8;
            af0[i] = *(const short8*)(ap);        // k 0..31
            af1[i] = *(const short8*)(ap + 32);   // k 32..63
        }
    }
    __syncthreads();   // all xs reads done; P/Q regions (overlapping xs) now writable

    // ---------------- Phase A2b: MFMA conv -> P/Q bf16 (swizzled) ------------
    // write: channel c = t*16+col -> region (col<8 ? P : Q), logical chunk t,
    //        physical byte = (t*16 ^ q<<4) + (col&7)*2, q = (pxr>>2)&3 (spreads kq groups)
    char* wbase = smc + (col < 8 ? 0 : QOFF);
    const int cb2 = (col & 7) * 2;
    #pragma unroll
    for (int i = 0; i < 4; ++i) {
        int mt = wv + i * 4;
        if (mt < 13) {
            floatx4 acc[8];
            #pragma unroll
            for (int t = 0; t < 8; ++t) acc[t] = (floatx4){0.f, 0.f, 0.f, 0.f};
            #pragma unroll
            for (int t = 0; t < 8; ++t) {
                acc[t] = __builtin_amdgcn_mfma_f32_16x16x32_bf16(af0[i], bw[t][0], acc[t], 0, 0, 0);
                acc[t] = __builtin_amdgcn_mfma_f32_16x16x32_bf16(af1[i], bw[t][1], acc[t], 0, 0, 0);
            }
            #pragma unroll
            for (int r = 0; r < 4; ++r) {
                int pxr = mt * 16 + kq * 4 + r;   // D row = (lane>>4)*4 + r
                if (pxr < 204) {
                    int py  = (pxr * 965) >> 15;
                    int pxx = pxr - py * 34;
                    int gh = h0 + py - 1, gw = w0 + pxx - 1;
                    bool inb = (gh >= 0 && gh < 128 && gw >= 0 && gw < 128);
                    char* prow = wbase + pxr * 128;
                    int qsw = ((pxr >> 2) & 3) << 4;
                    #pragma unroll
                    for (int t = 0; t < 8; ++t)
                        *(ushort*)(prow + (((t * 16) ^ qsw) + cb2)) =
                            f2bf(inb ? (acc[t][r] + bias[t]) : 0.f);
                }
            }
        }
    }
    __syncthreads();

    // ---------------- Phase B: 3x3 local attention, deferred stores ----------
    const int g  = tid & 7;                   // channel group: c0 = g*16
    const int ox = tid >> 3;                  // 0..31
    float oA[16], oB[16];

    COMPUTE_PASS(0, oA)                       // reads px rows 0..2
    COMPUTE_PASS(1, oB)                       // reads px rows 1..3
    __syncthreads();                          // bands 0-1 of P,Q fully read -> dead
    STAGE_PASS(oA)
    __syncthreads();
    COOP_STORE(0)
    __syncthreads();                          // WAR: restage over coop reads
    STAGE_PASS(oB)
    __syncthreads();
    COOP_STORE(1)
    COMPUTE_PASS(2, oA)                       // reads px rows 2..4 (disjoint from ostage)
    __syncthreads();                          // WAR: restage over coop reads
    STAGE_PASS(oA)
    __syncthreads();
    COOP_STORE(2)
    COMPUTE_PASS(3, oB)                       // reads px rows 3..5
    __syncthreads();
    STAGE_PASS(oB)
    __syncthreads();
    COOP_STORE(3)
}

extern "C" void kernel_launch(void* const* d_in, const int* in_sizes, int n_in,
                              void* d_out, int out_size, void* d_ws, size_t ws_size,
                              hipStream_t stream) {
    const float* x  = (const float*)d_in[0];
    const float* Wc = (const float*)d_in[1];
    const float* bc = (const float*)d_in[2];
    float* out = (float*)d_out;

    dim3 grid(1024);         // flat; XCD-chunked decode in-kernel
    dim3 block(256);
    attn_conv_fused<<<grid, block, 0, stream>>>(x, Wc, bc, out);
}

// Round 3
// 130.909 us; speedup vs baseline: 1.6730x; 1.6730x over previous
//
#include <hip/hip_runtime.h>
#include <hip/hip_bf16.h>

typedef __attribute__((ext_vector_type(8))) short short8;   // 8 x bf16 (4 VGPRs)
typedef __attribute__((ext_vector_type(4))) float floatx4;  // MFMA acc

#define XS_STRIDE 72    // ushorts; xs[204][72] = 29376 B at smem+0 (reused as ostage in phase B)
#define PBASE 29376     // P region: [204][128B], chunk g = channels g*16..+7 (bf16)
#define QBASE 55504     // Q region: [204][128B] at PBASE+26112+16; +16 staggers bank quads by 1
// chunk swizzle (both regions): physical 16B-chunk = logical ^ (px & 7)
//   phase-B reads: 8 ox-lanes (consecutive px) -> 8 distinct bank quads -> conflict-free b128
//   A2b scalar writes: 4 distinct quads ({t^r, t^r^4} in P, +1 in Q) -> 4-way (was 8-way)
// ostage: f32 [32 rows][512 B] at smem+0 (16384 B <= xs region), chunk swizzle ^ (ox & 7)
//   stage float4 writes conflict-free; coop b32 reads 2-way (free)
// LDS total 81632 B -> 2 blocks/CU (163264 <= 163840)

__device__ __forceinline__ ushort f2bf(float f) {
    union { __hip_bfloat16 h; ushort u; } cv;
    cv.h = __float2bfloat16(f);
    return cv.u;
}
__device__ __forceinline__ float bflo(unsigned int u) { return __uint_as_float(u << 16); }
__device__ __forceinline__ float bfhi(unsigned int u) { return __uint_as_float(u & 0xffff0000u); }

__device__ __forceinline__ float dot8(uint4 p, const float* cf) {
    return bflo(p.x)*cf[0] + bfhi(p.x)*cf[1] + bflo(p.y)*cf[2] + bfhi(p.y)*cf[3]
         + bflo(p.z)*cf[4] + bfhi(p.z)*cf[5] + bflo(p.w)*cf[6] + bfhi(p.w)*cf[7];
}
__device__ __forceinline__ void fma8(uint4 p, float a, float* o) {
    o[0] += a*bflo(p.x); o[1] += a*bfhi(p.x); o[2] += a*bflo(p.y); o[3] += a*bfhi(p.y);
    o[4] += a*bflo(p.z); o[5] += a*bfhi(p.z); o[6] += a*bflo(p.w); o[7] += a*bfhi(p.w);
}

// 8-lane (same-pixel) reduce: xor1/xor2 on VALU via DPP quad_perm, xor4 via shfl.
__device__ __forceinline__ float gsum8(float v) {
    v += __int_as_float(__builtin_amdgcn_update_dpp(0, __float_as_int(v), 0xB1, 0xF, 0xF, false)); // xor1
    v += __int_as_float(__builtin_amdgcn_update_dpp(0, __float_as_int(v), 0x4E, 0xF, 0xF, false)); // xor2
    v += __shfl_xor(v, 4);                                                                          // xor4
    return v;
}

__global__ __launch_bounds__(256, 2)
void attn_conv_fused(const float* __restrict__ x, const float* __restrict__ Wc,
                     const float* __restrict__ bc, float* __restrict__ out) {
    __shared__ __align__(16) unsigned char smem[81632];
    ushort* xs = (ushort*)smem;
    char* smc = (char*)smem;

    const int tid = threadIdx.x;
    // XCD-chunked swizzle (bijective, 1024 = 8*128): XCD k owns batch k entirely;
    // within an XCD, w-tiles fastest then h-bands -> halo rows stay L2-resident.
    const int rid = ((blockIdx.x & 7) << 7) | (blockIdx.x >> 3);
    const int b   = rid >> 7;
    const int h0  = ((rid >> 2) & 31) * 4;
    const int w0  = (rid & 3) * 32;
    const int lane = tid & 63;
    const int wv   = tid >> 6;

    // ---------------- Phase A0: stage x tile transposed -> xs[px][ci] bf16 ----
    if (tid < 204) {
        int py  = (tid * 965) >> 15;          // tid / 34 (exact for tid<208)
        int pxx = tid - py * 34;
        int gh = h0 + py - 1, gw = w0 + pxx - 1;
        bool inb = (gh >= 0 && gh < 128 && gw >= 0 && gw < 128);
        ushort* dst = xs + tid * XS_STRIDE;
        if (inb) {
            const float* xp = x + (b * 64) * 16384 + gh * 128 + gw;
            #pragma unroll
            for (int c0 = 0; c0 < 64; c0 += 4) {
                float v0 = xp[(c0 + 0) << 14];
                float v1 = xp[(c0 + 1) << 14];
                float v2 = xp[(c0 + 2) << 14];
                float v3 = xp[(c0 + 3) << 14];
                unsigned int u01 = (unsigned int)f2bf(v0) | ((unsigned int)f2bf(v1) << 16);
                unsigned int u23 = (unsigned int)f2bf(v2) | ((unsigned int)f2bf(v3) << 16);
                *(uint2*)(dst + c0) = make_uint2(u01, u23);
            }
        } else {
            #pragma unroll
            for (int c0 = 0; c0 < 64; c0 += 4)
                *(uint2*)(dst + c0) = make_uint2(0u, 0u);
        }
    }

    // ---------------- Phase A1: W fragments (B-operand) from global ----------
    const int col = lane & 15;
    const int kq  = lane >> 4;
    short8 bw[8][2];
    float  bias[8];
    #pragma unroll
    for (int t = 0; t < 8; ++t) {
        int c = t * 16 + col;
        bias[t] = bc[c];
        #pragma unroll
        for (int half = 0; half < 2; ++half) {
            const float* wp = Wc + c * 64 + half * 32 + kq * 8;
            float4 wa = *(const float4*)wp;
            float4 wb = *(const float4*)(wp + 4);
            short8 f;
            f[0] = (short)f2bf(wa.x); f[1] = (short)f2bf(wa.y);
            f[2] = (short)f2bf(wa.z); f[3] = (short)f2bf(wa.w);
            f[4] = (short)f2bf(wb.x); f[5] = (short)f2bf(wb.y);
            f[6] = (short)f2bf(wb.z); f[7] = (short)f2bf(wb.w);
            bw[t][half] = f;
        }
    }
    __syncthreads();

    // ---------------- Phase A2: MFMA conv -> P/Q bf16 (swizzled) -------------
    // write: channel c = t*16+col -> region (col<8 ? P : Q), chunk t ^ (pxr&7),
    //        ushort slot col&7.  xs and P/Q are disjoint -> no extra barrier.
    char* wbase = smc + (col < 8 ? PBASE : QBASE);
    const int cb2 = (col & 7) * 2;
    for (int mt = wv; mt < 13; mt += 4) {
        int pxa = mt * 16 + col;              // A-row pixel this lane reads
        const ushort* ap = xs + pxa * XS_STRIDE + kq * 8;
        short8 a0 = *(const short8*)(ap);          // k 0..31 slice
        short8 a1 = *(const short8*)(ap + 32);     // k 32..63 slice
        floatx4 acc[8];
        #pragma unroll
        for (int t = 0; t < 8; ++t) acc[t] = (floatx4){0.f, 0.f, 0.f, 0.f};
        #pragma unroll
        for (int t = 0; t < 8; ++t) {
            acc[t] = __builtin_amdgcn_mfma_f32_16x16x32_bf16(a0, bw[t][0], acc[t], 0, 0, 0);
            acc[t] = __builtin_amdgcn_mfma_f32_16x16x32_bf16(a1, bw[t][1], acc[t], 0, 0, 0);
        }
        #pragma unroll
        for (int r = 0; r < 4; ++r) {
            int pxr = mt * 16 + kq * 4 + r;   // D row = (lane>>4)*4 + r
            if (pxr < 204) {
                int py  = (pxr * 965) >> 15;
                int pxx = pxr - py * 34;
                int gh = h0 + py - 1, gw = w0 + pxx - 1;
                bool inb = (gh >= 0 && gh < 128 && gw >= 0 && gw < 128);
                char* prow = wbase + pxr * 128;
                int swz = (pxr & 7) << 4;
                #pragma unroll
                for (int t = 0; t < 8; ++t)
                    *(ushort*)(prow + (((t * 16) ^ swz) + cb2)) =
                        f2bf(inb ? (acc[t][r] + bias[t]) : 0.f);
            }
        }
    }
    __syncthreads();

    // ---------------- Phase B: 3x3 local attention, one row per pass ---------
    const int g  = tid & 7;                   // channel group: c0 = g*16
    const int ox = tid >> 3;                  // 0..31
    for (int oy = 0; oy < 4; ++oy) {
        int pc = (oy + 1) * 34 + (ox + 1);
        uint4 plo[9], phi[9];
        #pragma unroll
        for (int n = 0; n < 9; ++n) {
            int pi = pc + (n / 3 - 1) * 34 + (n % 3 - 1);
            const char* pp = smc + PBASE + pi * 128 + ((g * 16) ^ ((pi & 7) << 4));
            plo[n] = *(const uint4*)pp;
            phi[n] = *(const uint4*)(pp + (QBASE - PBASE));
        }
        float cf[16];
        {
            uint4 c0 = plo[4], c1 = phi[4];
            cf[0]=bflo(c0.x); cf[1]=bfhi(c0.x); cf[2]=bflo(c0.y); cf[3]=bfhi(c0.y);
            cf[4]=bflo(c0.z); cf[5]=bfhi(c0.z); cf[6]=bflo(c0.w); cf[7]=bfhi(c0.w);
            cf[8]=bflo(c1.x); cf[9]=bfhi(c1.x); cf[10]=bflo(c1.y); cf[11]=bfhi(c1.y);
            cf[12]=bflo(c1.z); cf[13]=bfhi(c1.z); cf[14]=bflo(c1.w); cf[15]=bfhi(c1.w);
        }
        float s[9];
        #pragma unroll
        for (int n = 0; n < 9; ++n)
            s[n] = dot8(plo[n], cf) + dot8(phi[n], cf + 8);
        #pragma unroll
        for (int n = 0; n < 9; ++n)
            s[n] = gsum8(s[n]) * 0.08838834764831845f;    // 1/sqrt(128)
        float m = s[0];
        #pragma unroll
        for (int n = 1; n < 9; ++n) m = fmaxf(m, s[n]);
        float e[9], sum = 0.f;
        #pragma unroll
        for (int n = 0; n < 9; ++n) { e[n] = __expf(s[n] - m); sum += e[n]; }
        float inv = 1.f / sum;

        float o[16];
        #pragma unroll
        for (int j = 0; j < 16; ++j) o[j] = 0.f;
        #pragma unroll
        for (int n = 0; n < 9; ++n) {
            float a = e[n] * inv;
            fma8(plo[n], a, o);
            fma8(phi[n], a, o + 8);
        }

        // stage to ostage row ox (512B rows, chunk ^ (ox&7)) for coalesced store
        {
            char* orow = smc + ox * 512;
            int xsw = ox & 7;
            #pragma unroll
            for (int k = 0; k < 4; ++k)
                *(float4*)(orow + (((g * 4 + k) ^ xsw) << 4)) =
                    make_float4(o[4*k], o[4*k+1], o[4*k+2], o[4*k+3]);
        }
        __syncthreads();

        // cooperative store: full 128B line per (c,row)
        {
            int c = tid >> 1, half = tid & 1;
            int lc = c >> 2, fo = (c & 3) << 2;
            float tmp[16];
            #pragma unroll
            for (int j = 0; j < 16; ++j) {
                int row = half * 16 + j;
                tmp[j] = *(const float*)(smc + row * 512 + ((lc ^ (row & 7)) << 4) + fo);
            }
            float* og = out + ((size_t)((b * 128 + c) * 128 + (h0 + oy))) * 128 + w0 + half * 16;
            #pragma unroll
            for (int k = 0; k < 4; ++k)
                *(float4*)(og + 4 * k) = make_float4(tmp[4*k], tmp[4*k+1], tmp[4*k+2], tmp[4*k+3]);
        }
        __syncthreads();
    }
}

extern "C" void kernel_launch(void* const* d_in, const int* in_sizes, int n_in,
                              void* d_out, int out_size, void* d_ws, size_t ws_size,
                              hipStream_t stream) {
    const float* x  = (const float*)d_in[0];
    const float* Wc = (const float*)d_in[1];
    const float* bc = (const float*)d_in[2];
    float* out = (float*)d_out;

    dim3 grid(1024);         // flat; XCD-chunked decode in-kernel
    dim3 block(256);
    attn_conv_fused<<<grid, block, 0, stream>>>(x, Wc, bc, out);
}

// Round 4
// 128.352 us; speedup vs baseline: 1.7063x; 1.0199x over previous
//
#include <hip/hip_runtime.h>
#include <hip/hip_bf16.h>

typedef __attribute__((ext_vector_type(8))) short short8;   // 8 x bf16 (4 VGPRs)
typedef __attribute__((ext_vector_type(4))) float floatx4;  // MFMA acc

#define XS_STRIDE 72    // ushorts; xs[204][72] = 29376 B at smem+0, DEAD after A2a reg-preload
#define QBASE 26128     // Q region at 26112+16: +16 staggers Q bank quads by 1 vs P
// LDS map (52,240 B total -> 3 blocks/CU, 156,720 <= 163,840):
//   P region [204][128B] at 0      : chunk g = channels g*16..+7 (bf16), overlays xs
//   Q region [204][128B] at 26128  : chunk g = channels g*16+8..+15
//   chunk swizzle: physical 16B-chunk = logical ^ (px & 7)
//     -> phase-B b128 reads: 8 g-lanes per px cover full row (banks 0-31 once) = conflict-free
//   ostage: after compute pass oy, P band oy (4352 B) + Q band oy (4352 B) are dead.
//     rows [32 ox][256 B] (64 channels x f32): ox 0..16 in P band, 17..31 in Q band.
//     Two channel-half passes (c 0..63, 64..127) per oy; stores are 64B-contiguous per
//     4-lane group -> full 128B lines per instruction pair.

__device__ __forceinline__ ushort f2bf(float f) {
    union { __hip_bfloat16 h; ushort u; } cv;
    cv.h = __float2bfloat16(f);
    return cv.u;
}
__device__ __forceinline__ float bflo(unsigned int u) { return __uint_as_float(u << 16); }
__device__ __forceinline__ float bfhi(unsigned int u) { return __uint_as_float(u & 0xffff0000u); }

__device__ __forceinline__ float dot8(uint4 p, const float* cf) {
    return bflo(p.x)*cf[0] + bfhi(p.x)*cf[1] + bflo(p.y)*cf[2] + bfhi(p.y)*cf[3]
         + bflo(p.z)*cf[4] + bfhi(p.z)*cf[5] + bflo(p.w)*cf[6] + bfhi(p.w)*cf[7];
}
__device__ __forceinline__ void fma8(uint4 p, float a, float* o) {
    o[0] += a*bflo(p.x); o[1] += a*bfhi(p.x); o[2] += a*bflo(p.y); o[3] += a*bfhi(p.y);
    o[4] += a*bflo(p.z); o[5] += a*bfhi(p.z); o[6] += a*bflo(p.w); o[7] += a*bfhi(p.w);
}

// 8-lane (same-pixel) reduce: xor1/xor2 on VALU via DPP quad_perm, xor4 via shfl.
__device__ __forceinline__ float gsum8(float v) {
    v += __int_as_float(__builtin_amdgcn_update_dpp(0, __float_as_int(v), 0xB1, 0xF, 0xF, false)); // xor1
    v += __int_as_float(__builtin_amdgcn_update_dpp(0, __float_as_int(v), 0x4E, 0xF, 0xF, false)); // xor2
    v += __shfl_xor(v, 4);                                                                          // xor4
    return v;
}

// ostage row base: rows 0..16 live in dead P band oy, rows 17..31 in dead Q band oy.
__device__ __forceinline__ char* orow_base(char* smc, int oy, int ox) {
    return smc + (ox < 17 ? oy * 4352 + ox * 256
                          : QBASE + oy * 4352 + (ox - 17) * 256);
}
// ostage chunk swizzle: distinct quads across the 4 rows a store lane-group touches
__device__ __forceinline__ int oswz(int ox) {
    return (ox & 7) ^ (((ox >> 3) & 3) << 1);
}

__global__ __launch_bounds__(256, 2)
void attn_conv_fused(const float* __restrict__ x, const float* __restrict__ Wc,
                     const float* __restrict__ bc, float* __restrict__ out) {
    __shared__ __align__(16) unsigned char smem[52240];
    ushort* xs = (ushort*)smem;
    char* smc = (char*)smem;

    const int tid = threadIdx.x;
    // XCD-chunked swizzle (bijective, 1024 = 8*128): XCD k owns batch k entirely;
    // within an XCD, w-tiles fastest then h-bands -> halo rows stay L2-resident.
    const int rid = ((blockIdx.x & 7) << 7) | (blockIdx.x >> 3);
    const int b   = rid >> 7;
    const int h0  = ((rid >> 2) & 31) * 4;
    const int w0  = (rid & 3) * 32;
    const int lane = tid & 63;
    const int wv   = tid >> 6;

    // ---------------- Phase A0: stage x tile transposed -> xs[px][ci] bf16 ----
    if (tid < 204) {
        int py  = (tid * 965) >> 15;          // tid / 34 (exact for tid<208)
        int pxx = tid - py * 34;
        int gh = h0 + py - 1, gw = w0 + pxx - 1;
        bool inb = (gh >= 0 && gh < 128 && gw >= 0 && gw < 128);
        ushort* dst = xs + tid * XS_STRIDE;
        if (inb) {
            const float* xp = x + (b * 64) * 16384 + gh * 128 + gw;
            #pragma unroll
            for (int c0 = 0; c0 < 64; c0 += 4) {
                float v0 = xp[(c0 + 0) << 14];
                float v1 = xp[(c0 + 1) << 14];
                float v2 = xp[(c0 + 2) << 14];
                float v3 = xp[(c0 + 3) << 14];
                unsigned int u01 = (unsigned int)f2bf(v0) | ((unsigned int)f2bf(v1) << 16);
                unsigned int u23 = (unsigned int)f2bf(v2) | ((unsigned int)f2bf(v3) << 16);
                *(uint2*)(dst + c0) = make_uint2(u01, u23);
            }
        } else {
            #pragma unroll
            for (int c0 = 0; c0 < 64; c0 += 4)
                *(uint2*)(dst + c0) = make_uint2(0u, 0u);
        }
    }

    // ---------------- Phase A1: W fragments (B-operand) from global ----------
    const int col = lane & 15;
    const int kq  = lane >> 4;
    short8 bw[8][2];
    float  bias[8];
    #pragma unroll
    for (int t = 0; t < 8; ++t) {
        int c = t * 16 + col;
        bias[t] = bc[c];
        #pragma unroll
        for (int half = 0; half < 2; ++half) {
            const float* wp = Wc + c * 64 + half * 32 + kq * 8;
            float4 wa = *(const float4*)wp;
            float4 wb = *(const float4*)(wp + 4);
            short8 f;
            f[0] = (short)f2bf(wa.x); f[1] = (short)f2bf(wa.y);
            f[2] = (short)f2bf(wa.z); f[3] = (short)f2bf(wa.w);
            f[4] = (short)f2bf(wb.x); f[5] = (short)f2bf(wb.y);
            f[6] = (short)f2bf(wb.z); f[7] = (short)f2bf(wb.w);
            bw[t][half] = f;
        }
    }
    __syncthreads();

    // ---------------- Phase A2a: preload this wave's A-fragments (xs dies) ----
    short8 af0[4], af1[4];
    #pragma unroll
    for (int i = 0; i < 4; ++i) {
        int mt = wv + i * 4;
        if (mt < 13) {
            const ushort* ap = xs + (mt * 16 + col) * XS_STRIDE + kq * 8;
            af0[i] = *(const short8*)(ap);        // k 0..31
            af1[i] = *(const short8*)(ap + 32);   // k 32..63
        }
    }
    __syncthreads();   // all xs reads done; P/Q (overlaying xs) now writable

    // ---------------- Phase A2b: MFMA conv -> P/Q bf16 (swizzled) ------------
    // channel c = t*16+col -> region (col<8 ? P : Q), chunk t ^ (pxr&7), slot col&7
    char* wbase = smc + (col < 8 ? 0 : QBASE);
    const int cb2 = (col & 7) * 2;
    #pragma unroll
    for (int i = 0; i < 4; ++i) {
        int mt = wv + i * 4;
        if (mt < 13) {
            floatx4 acc[8];
            #pragma unroll
            for (int t = 0; t < 8; ++t) acc[t] = (floatx4){0.f, 0.f, 0.f, 0.f};
            #pragma unroll
            for (int t = 0; t < 8; ++t) {
                acc[t] = __builtin_amdgcn_mfma_f32_16x16x32_bf16(af0[i], bw[t][0], acc[t], 0, 0, 0);
                acc[t] = __builtin_amdgcn_mfma_f32_16x16x32_bf16(af1[i], bw[t][1], acc[t], 0, 0, 0);
            }
            #pragma unroll
            for (int r = 0; r < 4; ++r) {
                int pxr = mt * 16 + kq * 4 + r;   // D row = (lane>>4)*4 + r
                if (pxr < 204) {
                    int py  = (pxr * 965) >> 15;
                    int pxx = pxr - py * 34;
                    int gh = h0 + py - 1, gw = w0 + pxx - 1;
                    bool inb = (gh >= 0 && gh < 128 && gw >= 0 && gw < 128);
                    char* prow = wbase + pxr * 128;
                    int swz = (pxr & 7) << 4;
                    #pragma unroll
                    for (int t = 0; t < 8; ++t)
                        *(ushort*)(prow + (((t * 16) ^ swz) + cb2)) =
                            f2bf(inb ? (acc[t][r] + bias[t]) : 0.f);
                }
            }
        }
    }
    __syncthreads();

    // ---------------- Phase B: 3x3 local attention, one row per pass ---------
    const int g  = tid & 7;                   // channel group: c0 = g*16
    const int ox = tid >> 3;                  // 0..31
    const int osw = oswz(ox);
    for (int oy = 0; oy < 4; ++oy) {
        int pc = (oy + 1) * 34 + (ox + 1);
        uint4 plo[9], phi[9];
        #pragma unroll
        for (int n = 0; n < 9; ++n) {
            int pi = pc + (n / 3 - 1) * 34 + (n % 3 - 1);
            const char* pp = smc + pi * 128 + ((g * 16) ^ ((pi & 7) << 4));
            plo[n] = *(const uint4*)pp;
            phi[n] = *(const uint4*)(pp + QBASE);
        }
        float cf[16];
        {
            uint4 c0 = plo[4], c1 = phi[4];
            cf[0]=bflo(c0.x); cf[1]=bfhi(c0.x); cf[2]=bflo(c0.y); cf[3]=bfhi(c0.y);
            cf[4]=bflo(c0.z); cf[5]=bfhi(c0.z); cf[6]=bflo(c0.w); cf[7]=bfhi(c0.w);
            cf[8]=bflo(c1.x); cf[9]=bfhi(c1.x); cf[10]=bflo(c1.y); cf[11]=bfhi(c1.y);
            cf[12]=bflo(c1.z); cf[13]=bfhi(c1.z); cf[14]=bflo(c1.w); cf[15]=bfhi(c1.w);
        }
        float s[9];
        #pragma unroll
        for (int n = 0; n < 9; ++n)
            s[n] = dot8(plo[n], cf) + dot8(phi[n], cf + 8);
        #pragma unroll
        for (int n = 0; n < 9; ++n)
            s[n] = gsum8(s[n]) * 0.08838834764831845f;    // 1/sqrt(128)
        float m = s[0];
        #pragma unroll
        for (int n = 1; n < 9; ++n) m = fmaxf(m, s[n]);
        float e[9], sum = 0.f;
        #pragma unroll
        for (int n = 0; n < 9; ++n) { e[n] = __expf(s[n] - m); sum += e[n]; }
        float inv = 1.f / sum;

        float o[16];
        #pragma unroll
        for (int j = 0; j < 16; ++j) o[j] = 0.f;
        #pragma unroll
        for (int n = 0; n < 9; ++n) {
            float a = e[n] * inv;
            fma8(plo[n], a, o);
            fma8(phi[n], a, o + 8);
        }

        // ---- store via two channel-half passes through dead band oy ----
        #pragma unroll
        for (int H = 0; H < 2; ++H) {
            __syncthreads();                  // H=0: band oy reads done; H=1: WAR vs prev store reads
            if ((g >> 2) == H) {              // stage this thread's 16 channels (c = g*16..+15)
                char* rb = orow_base(smc, oy, ox);
                int gg = g & 3;
                #pragma unroll
                for (int k = 0; k < 4; ++k)
                    *(float4*)(rb + (((gg * 4 + k) ^ osw) << 4)) =
                        make_float4(o[4*k], o[4*k+1], o[4*k+2], o[4*k+3]);
            }
            __syncthreads();
            {
                int cl = tid >> 2, q = tid & 3;       // cl 0..63, q 0..3
                int c  = H * 64 + cl;
                float tmp[8];
                #pragma unroll
                for (int j = 0; j < 8; ++j) {
                    int oxr = (j < 4) ? (q * 4 + j) : (16 + q * 4 + (j - 4));
                    const char* rb = orow_base(smc, oy, oxr);
                    tmp[j] = *(const float*)(rb + (((cl >> 2) ^ oswz(oxr)) << 4) + ((cl & 3) << 2));
                }
                float* og = out + ((size_t)((b * 128 + c) * 128 + (h0 + oy))) * 128 + w0;
                *(float4*)(og + q * 4)      = make_float4(tmp[0], tmp[1], tmp[2], tmp[3]);
                *(float4*)(og + 16 + q * 4) = make_float4(tmp[4], tmp[5], tmp[6], tmp[7]);
            }
        }
        // next compute reads bands oy+1..oy+3: disjoint from band-oy stage/store region
    }
}

extern "C" void kernel_launch(void* const* d_in, const int* in_sizes, int n_in,
                              void* d_out, int out_size, void* d_ws, size_t ws_size,
                              hipStream_t stream) {
    const float* x  = (const float*)d_in[0];
    const float* Wc = (const float*)d_in[1];
    const float* bc = (const float*)d_in[2];
    float* out = (float*)d_out;

    dim3 grid(1024);         // flat; XCD-chunked decode in-kernel
    dim3 block(256);
    attn_conv_fused<<<grid, block, 0, stream>>>(x, Wc, bc, out);
}

// Round 5
// 127.392 us; speedup vs baseline: 1.7192x; 1.0075x over previous
//
#include <hip/hip_runtime.h>
#include <hip/hip_bf16.h>

typedef __attribute__((ext_vector_type(8))) short short8;   // 8 x bf16 (4 VGPRs)
typedef __attribute__((ext_vector_type(4))) float floatx4;  // MFMA acc
typedef __attribute__((ext_vector_type(2))) float floatx2;  // packed f32 (v_pk_*_f32)

#define XS_STRIDE 72    // ushorts; xs[204][72] = 29376 B at smem+0, DEAD after A2a reg-preload
#define QBASE 26128     // Q region at 26112+16: +16 staggers Q bank quads by 1 vs P
// LDS map (52,240 B total -> 3 blocks/CU):
//   P region [204][128B] at 0      : chunk g = channels g*16..+7 (bf16), overlays xs
//   Q region [204][128B] at 26128  : chunk g = channels g*16+8..+15
//   chunk swizzle: physical 16B-chunk = logical ^ (px & 7)
// Phase B is BARRIER-FREE: no ostage. Output is stored directly per-channel
// (store_dword, 8 x 32B segments per wave-instruction); the 4 waves of a block
// complete each 128B line in L2 (write-back, working set << 4MB/XCD) -> full-line
// writebacks, no amplification. WRITE_SIZE is the falsifier.

__device__ __forceinline__ ushort f2bf(float f) {
    union { __hip_bfloat16 h; ushort u; } cv;
    cv.h = __float2bfloat16(f);
    return cv.u;
}
__device__ __forceinline__ float bflo(unsigned int u) { return __uint_as_float(u << 16); }
__device__ __forceinline__ float bfhi(unsigned int u) { return __uint_as_float(u & 0xffff0000u); }
__device__ __forceinline__ floatx2 bf2f2(unsigned int u) {
    floatx2 r; r.x = __uint_as_float(u << 16); r.y = __uint_as_float(u & 0xffff0000u); return r;
}
// packed PV accumulate: 4 x v_pk_fma_f32 per uint4 (8 channels)
__device__ __forceinline__ void fmaacc(uint4 p, floatx2 a2, floatx2* o2) {
    o2[0] += a2 * bf2f2(p.x); o2[1] += a2 * bf2f2(p.y);
    o2[2] += a2 * bf2f2(p.z); o2[3] += a2 * bf2f2(p.w);
}

// 8-lane (same-pixel) reduce: xor1/xor2 on VALU via DPP quad_perm, xor4 via shfl.
__device__ __forceinline__ float gsum8(float v) {
    v += __int_as_float(__builtin_amdgcn_update_dpp(0, __float_as_int(v), 0xB1, 0xF, 0xF, false)); // xor1
    v += __int_as_float(__builtin_amdgcn_update_dpp(0, __float_as_int(v), 0x4E, 0xF, 0xF, false)); // xor2
    v += __shfl_xor(v, 4);                                                                          // xor4
    return v;
}

// ---- phase-B building blocks (macros: compile-time slot indices -> registers) ----
#define LOADROW(S, PROW)                                                            \
    {                                                                               \
        _Pragma("unroll")                                                           \
        for (int dx = 0; dx < 3; ++dx) {                                            \
            int pi = (PROW) * 34 + ox + dx;                                         \
            const char* pp = smc + pi * 128 + ((g * 16) ^ ((pi & 7) << 4));         \
            wlo[S][dx] = *(const uint4*)pp;                                         \
            whi[S][dx] = *(const uint4*)(pp + QBASE);                               \
        }                                                                           \
    }

#define SCORE1(S, DX) ({                                                            \
        uint4 _l = wlo[S][DX], _h = whi[S][DX];                                     \
        floatx2 _s = bf2f2(_l.x) * cf2[0];                                          \
        _s += bf2f2(_l.y) * cf2[1];                                                 \
        _s += bf2f2(_l.z) * cf2[2];                                                 \
        _s += bf2f2(_l.w) * cf2[3];                                                 \
        _s += bf2f2(_h.x) * cf2[4];                                                 \
        _s += bf2f2(_h.y) * cf2[5];                                                 \
        _s += bf2f2(_h.z) * cf2[6];                                                 \
        _s += bf2f2(_h.w) * cf2[7];                                                 \
        _s.x + _s.y; })

#define PV(S, DX, A)                                                                \
    {                                                                               \
        floatx2 _a2; _a2.x = (A); _a2.y = (A);                                      \
        fmaacc(wlo[S][DX], _a2, o2);                                                \
        fmaacc(whi[S][DX], _a2, o2 + 4);                                            \
    }

#define ATTN_OY(OY, ST, SM, SB)                                                     \
    {                                                                               \
        floatx2 cf2[8];                                                             \
        {                                                                           \
            uint4 c0 = wlo[SM][1], c1 = whi[SM][1];                                 \
            cf2[0] = bf2f2(c0.x); cf2[1] = bf2f2(c0.y);                             \
            cf2[2] = bf2f2(c0.z); cf2[3] = bf2f2(c0.w);                             \
            cf2[4] = bf2f2(c1.x); cf2[5] = bf2f2(c1.y);                             \
            cf2[6] = bf2f2(c1.z); cf2[7] = bf2f2(c1.w);                             \
        }                                                                           \
        float s[9];                                                                 \
        s[0] = SCORE1(ST, 0); s[1] = SCORE1(ST, 1); s[2] = SCORE1(ST, 2);           \
        s[3] = SCORE1(SM, 0); s[4] = SCORE1(SM, 1); s[5] = SCORE1(SM, 2);           \
        s[6] = SCORE1(SB, 0); s[7] = SCORE1(SB, 1); s[8] = SCORE1(SB, 2);           \
        _Pragma("unroll")                                                           \
        for (int n = 0; n < 9; ++n)                                                 \
            s[n] = gsum8(s[n]) * 0.08838834764831845f;  /* 1/sqrt(128) */           \
        float m = s[0];                                                             \
        _Pragma("unroll")                                                           \
        for (int n = 1; n < 9; ++n) m = fmaxf(m, s[n]);                             \
        float e[9], sum = 0.f;                                                      \
        _Pragma("unroll")                                                           \
        for (int n = 0; n < 9; ++n) { e[n] = __expf(s[n] - m); sum += e[n]; }       \
        floatx2 o2[8];                                                              \
        _Pragma("unroll")                                                           \
        for (int k = 0; k < 8; ++k) { o2[k].x = 0.f; o2[k].y = 0.f; }               \
        PV(ST, 0, e[0]) PV(ST, 1, e[1]) PV(ST, 2, e[2])                             \
        PV(SM, 0, e[3]) PV(SM, 1, e[4]) PV(SM, 2, e[5])                             \
        PV(SB, 0, e[6]) PV(SB, 1, e[7]) PV(SB, 2, e[8])                             \
        float inv = 1.f / sum;                                                      \
        floatx2 inv2; inv2.x = inv; inv2.y = inv;                                   \
        float* og = out + ((size_t)((b * 128 + g * 16) * 128 + (h0 + (OY)))) * 128  \
                    + w0 + ox;                                                      \
        _Pragma("unroll")                                                           \
        for (int k = 0; k < 8; ++k) {                                               \
            floatx2 v = o2[k] * inv2;                                               \
            og[(2 * k) * 16384]     = v.x;                                          \
            og[(2 * k + 1) * 16384] = v.y;                                          \
        }                                                                           \
    }

__global__ __launch_bounds__(256, 2)
void attn_conv_fused(const float* __restrict__ x, const float* __restrict__ Wc,
                     const float* __restrict__ bc, float* __restrict__ out) {
    __shared__ __align__(16) unsigned char smem[52240];
    ushort* xs = (ushort*)smem;
    char* smc = (char*)smem;

    const int tid = threadIdx.x;
    // XCD-chunked swizzle (bijective, 1024 = 8*128): XCD k owns batch k entirely;
    // within an XCD, w-tiles fastest then h-bands -> halo rows stay L2-resident.
    const int rid = ((blockIdx.x & 7) << 7) | (blockIdx.x >> 3);
    const int b   = rid >> 7;
    const int h0  = ((rid >> 2) & 31) * 4;
    const int w0  = (rid & 3) * 32;
    const int lane = tid & 63;
    const int wv   = tid >> 6;

    // ---------------- Phase A0: stage x tile transposed -> xs[px][ci] bf16 ----
    if (tid < 204) {
        int py  = (tid * 965) >> 15;          // tid / 34 (exact for tid<208)
        int pxx = tid - py * 34;
        int gh = h0 + py - 1, gw = w0 + pxx - 1;
        bool inb = (gh >= 0 && gh < 128 && gw >= 0 && gw < 128);
        ushort* dst = xs + tid * XS_STRIDE;
        if (inb) {
            const float* xp = x + (b * 64) * 16384 + gh * 128 + gw;
            #pragma unroll
            for (int c0 = 0; c0 < 64; c0 += 4) {
                float v0 = xp[(c0 + 0) << 14];
                float v1 = xp[(c0 + 1) << 14];
                float v2 = xp[(c0 + 2) << 14];
                float v3 = xp[(c0 + 3) << 14];
                unsigned int u01 = (unsigned int)f2bf(v0) | ((unsigned int)f2bf(v1) << 16);
                unsigned int u23 = (unsigned int)f2bf(v2) | ((unsigned int)f2bf(v3) << 16);
                *(uint2*)(dst + c0) = make_uint2(u01, u23);
            }
        } else {
            #pragma unroll
            for (int c0 = 0; c0 < 64; c0 += 4)
                *(uint2*)(dst + c0) = make_uint2(0u, 0u);
        }
    }

    // ---------------- Phase A1: W fragments (B-operand) from global ----------
    const int col = lane & 15;
    const int kq  = lane >> 4;
    short8 bw[8][2];
    float  bias[8];
    #pragma unroll
    for (int t = 0; t < 8; ++t) {
        int c = t * 16 + col;
        bias[t] = bc[c];
        #pragma unroll
        for (int half = 0; half < 2; ++half) {
            const float* wp = Wc + c * 64 + half * 32 + kq * 8;
            float4 wa = *(const float4*)wp;
            float4 wb = *(const float4*)(wp + 4);
            short8 f;
            f[0] = (short)f2bf(wa.x); f[1] = (short)f2bf(wa.y);
            f[2] = (short)f2bf(wa.z); f[3] = (short)f2bf(wa.w);
            f[4] = (short)f2bf(wb.x); f[5] = (short)f2bf(wb.y);
            f[6] = (short)f2bf(wb.z); f[7] = (short)f2bf(wb.w);
            bw[t][half] = f;
        }
    }
    __syncthreads();

    // ---------------- Phase A2a: preload this wave's A-fragments (xs dies) ----
    short8 af0[4], af1[4];
    #pragma unroll
    for (int i = 0; i < 4; ++i) {
        int mt = wv + i * 4;
        if (mt < 13) {
            const ushort* ap = xs + (mt * 16 + col) * XS_STRIDE + kq * 8;
            af0[i] = *(const short8*)(ap);        // k 0..31
            af1[i] = *(const short8*)(ap + 32);   // k 32..63
        }
    }
    __syncthreads();   // all xs reads done; P/Q (overlaying xs) now writable

    // ---------------- Phase A2b: MFMA conv -> P/Q bf16 (swizzled) ------------
    // channel c = t*16+col -> region (col<8 ? P : Q), chunk t ^ (pxr&7), slot col&7
    char* wbase = smc + (col < 8 ? 0 : QBASE);
    const int cb2 = (col & 7) * 2;
    #pragma unroll
    for (int i = 0; i < 4; ++i) {
        int mt = wv + i * 4;
        if (mt < 13) {
            floatx4 acc[8];
            #pragma unroll
            for (int t = 0; t < 8; ++t) acc[t] = (floatx4){0.f, 0.f, 0.f, 0.f};
            #pragma unroll
            for (int t = 0; t < 8; ++t) {
                acc[t] = __builtin_amdgcn_mfma_f32_16x16x32_bf16(af0[i], bw[t][0], acc[t], 0, 0, 0);
                acc[t] = __builtin_amdgcn_mfma_f32_16x16x32_bf16(af1[i], bw[t][1], acc[t], 0, 0, 0);
            }
            #pragma unroll
            for (int r = 0; r < 4; ++r) {
                int pxr = mt * 16 + kq * 4 + r;   // D row = (lane>>4)*4 + r
                if (pxr < 204) {
                    int py  = (pxr * 965) >> 15;
                    int pxx = pxr - py * 34;
                    int gh = h0 + py - 1, gw = w0 + pxx - 1;
                    bool inb = (gh >= 0 && gh < 128 && gw >= 0 && gw < 128);
                    char* prow = wbase + pxr * 128;
                    int swz = (pxr & 7) << 4;
                    #pragma unroll
                    for (int t = 0; t < 8; ++t)
                        *(ushort*)(prow + (((t * 16) ^ swz) + cb2)) =
                            f2bf(inb ? (acc[t][r] + bias[t]) : 0.f);
                }
            }
        }
    }
    __syncthreads();   // LAST barrier: phase B is read-only on LDS, fully async

    // ---------------- Phase B: 3x3 local attention, barrier-free -------------
    // thread (g, ox): channels g*16..+15, pixel column ox; patch window carried
    // in registers across oy (rows oy..oy+2 of padded tile; reuse 2 of 3 rows).
    const int g  = tid & 7;                   // channel group: c0 = g*16
    const int ox = tid >> 3;                  // 0..31
    uint4 wlo[3][3], whi[3][3];               // [row slot][dx], lo=P chunk, hi=Q chunk

    LOADROW(0, 0) LOADROW(1, 1) LOADROW(2, 2)
    ATTN_OY(0, 0, 1, 2)
    LOADROW(0, 3)
    ATTN_OY(1, 1, 2, 0)
    LOADROW(1, 4)
    ATTN_OY(2, 2, 0, 1)
    LOADROW(2, 5)
    ATTN_OY(3, 0, 1, 2)
}

extern "C" void kernel_launch(void* const* d_in, const int* in_sizes, int n_in,
                              void* d_out, int out_size, void* d_ws, size_t ws_size,
                              hipStream_t stream) {
    const float* x  = (const float*)d_in[0];
    const float* Wc = (const float*)d_in[1];
    const float* bc = (const float*)d_in[2];
    float* out = (float*)d_out;

    dim3 grid(1024);         // flat; XCD-chunked decode in-kernel
    dim3 block(256);
    attn_conv_fused<<<grid, block, 0, stream>>>(x, Wc, bc, out);
}